// Round 3
// baseline (700.381 us; speedup 1.0000x reference)
//
#include <hip/hip_runtime.h>
#include <stdint.h>

// ---------------------------------------------------------------------------
// Attention block: out = softmax_causal( rope(xWq) rope(xWk)^T / sqrt(hd) ) (xWv) @ Wo
// B=2 T=2048 D=2048 H=16 KVH=4 hd=128. All fp32 in/out; internal bf16 MFMA.
// ---------------------------------------------------------------------------

#define T_SEQ 2048
#define NHEAD 16
#define NKVH  4
#define HD    128
#define BT    4096   // B*T

typedef unsigned short u16;
typedef __attribute__((ext_vector_type(8))) __bf16 bf16x8;
typedef __attribute__((ext_vector_type(8))) u16    u16x8;
typedef __attribute__((ext_vector_type(4))) u16    u16x4;
typedef __attribute__((ext_vector_type(4))) float  f32x4;

// fp32 -> bf16 RNE (finite inputs)
__device__ __forceinline__ u16 f2bf(float f) {
  uint32_t x = __float_as_uint(f);
  return (u16)((x + 0x7FFFu + ((x >> 16) & 1u)) >> 16);
}
__device__ __forceinline__ float bf2f(u16 u) {
  return __uint_as_float(((uint32_t)u) << 16);
}

// async global->LDS, 16B per lane (wave-uniform base + lane*16 dest)
__device__ __forceinline__ void gll16(const void* g, void* l) {
  __builtin_amdgcn_global_load_lds(
      (const __attribute__((address_space(1))) unsigned int*)g,
      (__attribute__((address_space(3))) unsigned int*)l, 16, 0, 0);
}

// ---------------------------------------------------------------------------
// prep kernels
// ---------------------------------------------------------------------------
__global__ __launch_bounds__(256) void k_cast_x(const float* __restrict__ src,
                                                u16* __restrict__ dst) {
  size_t id = (size_t)blockIdx.x * 256 + threadIdx.x;  // one float4 per thread
  f32x4 v = *reinterpret_cast<const f32x4*>(src + id * 4);
  u16x4 o;
  o[0] = f2bf(v[0]); o[1] = f2bf(v[1]); o[2] = f2bf(v[2]); o[3] = f2bf(v[3]);
  *reinterpret_cast<u16x4*>(dst + id * 4) = o;
}

// src [R][C] f32 (row-major) -> dst [C][R] bf16
__global__ __launch_bounds__(256) void k_transpose_cast(const float* __restrict__ src,
                                                        u16* __restrict__ dst,
                                                        int R, int C) {
  __shared__ float tile[32][33];
  int c0 = blockIdx.x * 32, r0 = blockIdx.y * 32;
  int tx = threadIdx.x & 31, ty = threadIdx.x >> 5;  // 32 x 8
#pragma unroll
  for (int i = 0; i < 4; ++i)
    tile[ty + i * 8][tx] = src[(size_t)(r0 + ty + i * 8) * C + c0 + tx];
  __syncthreads();
#pragma unroll
  for (int i = 0; i < 4; ++i)
    dst[(size_t)(c0 + ty + i * 8) * R + r0 + tx] = f2bf(tile[tx][ty + i * 8]);
}

// V [slice][t][d] bf16 -> Vt [slice][d][t] bf16, slice = b*NKVH+kvh
__global__ __launch_bounds__(256) void k_transpose_v(const u16* __restrict__ src,
                                                     u16* __restrict__ dst) {
  __shared__ u16 tile[32][34];
  int slice = blockIdx.z;
  src += (size_t)slice * T_SEQ * HD;
  dst += (size_t)slice * HD * T_SEQ;
  int d0 = blockIdx.x * 32, t0 = blockIdx.y * 32;
  int tx = threadIdx.x & 31, ty = threadIdx.x >> 5;
#pragma unroll
  for (int i = 0; i < 4; ++i)
    tile[ty + i * 8][tx] = src[(size_t)(t0 + ty + i * 8) * HD + d0 + tx];
  __syncthreads();
#pragma unroll
  for (int i = 0; i < 4; ++i)
    dst[(size_t)(d0 + ty + i * 8) * T_SEQ + t0 + tx] = tile[tx][ty + i * 8];
}

// cos/sin tables [T][64] fp32; freq_i = 10000^(-i/64)
__global__ __launch_bounds__(256) void k_rope_tables(float* __restrict__ tc,
                                                     float* __restrict__ ts) {
  int id = blockIdx.x * 256 + threadIdx.x;  // < 2048*64
  int pos = id >> 6, i = id & 63;
  float freq = exp2f(-(float)i * (13.287712379549449f / 64.0f));
  float ang = (float)pos * freq;
  tc[id] = cosf(ang);
  ts[id] = sinf(ang);
}

// in-place RoPE on [BH][T][128] bf16; scale folds 1/sqrt(hd) into Q
__global__ __launch_bounds__(256) void k_rope_apply(u16* __restrict__ buf,
                                                    const float* __restrict__ tc,
                                                    const float* __restrict__ ts,
                                                    float scale) {
  int id = blockIdx.x * 256 + threadIdx.x;
  int i8 = id & 15;                 // 8-elem chunk within head dim (4 pairs)
  int t  = (id >> 4) & (T_SEQ - 1);
  int bh = id >> 15;
  u16* p = buf + ((size_t)bh * T_SEQ + t) * HD + i8 * 8;
  u16x8 v = *reinterpret_cast<u16x8*>(p);
  f32x4 c = *reinterpret_cast<const f32x4*>(tc + t * 64 + i8 * 4);
  f32x4 s = *reinterpret_cast<const f32x4*>(ts + t * 64 + i8 * 4);
  u16x8 o;
#pragma unroll
  for (int j = 0; j < 4; ++j) {
    float x1 = bf2f(v[2 * j]), x2 = bf2f(v[2 * j + 1]);
    o[2 * j]     = f2bf((x1 * c[j] - x2 * s[j]) * scale);
    o[2 * j + 1] = f2bf((x1 * s[j] + x2 * c[j]) * scale);
  }
  *reinterpret_cast<u16x8*>(p) = o;
}

// ---------------------------------------------------------------------------
// m97-structure bf16 GEMM: C[M=4096][N] = A[4096][2048] * W, W given as Wt[N][2048].
// 128x128 tile, BK=32, 4 waves (2x2 of 64x64), global_load_lds staging.
// EPI=0: N=3072 fused QKV, epilogue scatters bf16 into Q/K/V head layouts.
// EPI=1: N=2048, epilogue stores fp32 to Cf.
// ---------------------------------------------------------------------------
template <int EPI>
__global__ __launch_bounds__(256) void k_gemm(const u16* __restrict__ A,
                                              const u16* __restrict__ W0,
                                              const u16* __restrict__ W1,
                                              const u16* __restrict__ W2,
                                              u16* __restrict__ Qb,
                                              u16* __restrict__ Kb,
                                              u16* __restrict__ Vb,
                                              float* __restrict__ Cf) {
  __shared__ u16 As[128 * 32];
  __shared__ u16 Bs[128 * 32];
  int t = threadIdx.x;
  int bx = blockIdx.x, by = blockIdx.y;
  int ncol0 = bx * 128;
  const u16* Bt;
  if (EPI == 0) {
    if (ncol0 < 2048)      Bt = W0 + (size_t)ncol0 * 2048;
    else if (ncol0 < 2560) Bt = W1 + (size_t)(ncol0 - 2048) * 2048;
    else                   Bt = W2 + (size_t)(ncol0 - 2560) * 2048;
  } else {
    Bt = W0 + (size_t)ncol0 * 2048;
  }
  const u16* ga = A  + (size_t)(by * 128 + (t >> 2)) * 2048 + (t & 3) * 8;
  const u16* gb = Bt + (size_t)(t >> 2) * 2048 + (t & 3) * 8;
  int w = t >> 6, l = t & 63;
  int wr = w >> 1, wc = w & 1;
  int lr = l & 15, lh = l >> 4;
  f32x4 acc[4][4] = {};
  for (int kb = 0; kb < 2048; kb += 32) {
    __syncthreads();
    gll16(ga,             &As[t * 8]);
    gll16(ga + 64 * 2048, &As[2048 + t * 8]);
    gll16(gb,             &Bs[t * 8]);
    gll16(gb + 64 * 2048, &Bs[2048 + t * 8]);
    ga += 32; gb += 32;
    __syncthreads();
    bf16x8 af[4], bw[4];
#pragma unroll
    for (int fr = 0; fr < 4; ++fr)
      af[fr] = *reinterpret_cast<const bf16x8*>(&As[(wr * 64 + fr * 16 + lr) * 32 + lh * 8]);
#pragma unroll
    for (int fc = 0; fc < 4; ++fc)
      bw[fc] = *reinterpret_cast<const bf16x8*>(&Bs[(wc * 64 + fc * 16 + lr) * 32 + lh * 8]);
#pragma unroll
    for (int fr = 0; fr < 4; ++fr)
#pragma unroll
      for (int fc = 0; fc < 4; ++fc)
        acc[fr][fc] = __builtin_amdgcn_mfma_f32_16x16x32_bf16(af[fr], bw[fc], acc[fr][fc], 0, 0, 0);
  }
  int row0 = by * 128 + wr * 64;
  int col0 = ncol0 + wc * 64;
#pragma unroll
  for (int fr = 0; fr < 4; ++fr)
#pragma unroll
    for (int fc = 0; fc < 4; ++fc)
#pragma unroll
      for (int r = 0; r < 4; ++r) {
        int row = row0 + fr * 16 + lh * 4 + r;   // C/D: row=(l>>4)*4+reg, col=l&15
        int col = col0 + fc * 16 + lr;
        float v = acc[fr][fc][r];
        if (EPI == 1) {
          Cf[(size_t)row * 2048 + col] = v;
        } else {
          int b = row >> 11, tt = row & 2047;
          if (col < 2048) {
            int h = col >> 7, d = col & 127;
            Qb[((size_t)(b * NHEAD + h) * T_SEQ + tt) * HD + d] = f2bf(v);
          } else if (col < 2560) {
            int c2 = col - 2048; int h = c2 >> 7, d = c2 & 127;
            Kb[((size_t)(b * NKVH + h) * T_SEQ + tt) * HD + d] = f2bf(v);
          } else {
            int c2 = col - 2560; int h = c2 >> 7, d = c2 & 127;
            Vb[((size_t)(b * NKVH + h) * T_SEQ + tt) * HD + d] = f2bf(v);
          }
        }
      }
}

// ---------------------------------------------------------------------------
// Flash attention (causal, GQA). Grid: b*512 + h*32 + qblk; 4 waves/block,
// wave w owns q-rows [qblk*64 + w*16, +16). KV tiles of 64; K/V read direct
// from global (L2-resident, 1MB per (b,kvh)); online softmax in registers;
// P->bf16 via per-wave padded LDS (NO barriers needed: per-wave data only,
// in-wave ds_write->ds_read ordering is lgkmcnt-enforced by the compiler);
// PV from pre-transposed Vt[d][t]. Scale pre-folded into Q by k_rope_apply.
// ---------------------------------------------------------------------------
__global__ __launch_bounds__(256) void k_attn(const u16* __restrict__ Q,
                                              const u16* __restrict__ K,
                                              const u16* __restrict__ Vt,
                                              u16* __restrict__ O) {
  int blk = blockIdx.x;
  int qblk = blk & 31, h = (blk >> 5) & 15, b = blk >> 9;
  int kvh = h >> 2;
  int w = threadIdx.x >> 6, l = threadIdx.x & 63;
  int lr = l & 15, lh = l >> 4;
  int qrow0 = qblk * 64 + w * 16;
  const u16* Qp = Q  + ((size_t)(b * NHEAD + h) * T_SEQ) * HD;
  const u16* Kp = K  + ((size_t)(b * NKVH + kvh) * T_SEQ) * HD;
  const u16* Vp = Vt + ((size_t)(b * NKVH + kvh) * HD) * T_SEQ;  // [d][t]

  __shared__ u16 Plds[4][16][72];  // stride 72 (144B) -> 2-way conflicts only

  bf16x8 qf[4];
#pragma unroll
  for (int ks = 0; ks < 4; ++ks)
    qf[ks] = *reinterpret_cast<const bf16x8*>(Qp + (size_t)(qrow0 + lr) * HD + ks * 32 + lh * 8);

  f32x4 o[8] = {};
  float mrun[4], lrun[4];
#pragma unroll
  for (int r = 0; r < 4; ++r) { mrun[r] = -1e30f; lrun[r] = 0.f; }

  int ntiles = qblk + 1;
  for (int it = 0; it < ntiles; ++it) {
    int t0 = it * 64;
    // S = Q K^T : 4 col-tiles x 4 d-steps
    f32x4 s[4] = {};
#pragma unroll
    for (int ct = 0; ct < 4; ++ct)
#pragma unroll
      for (int ks = 0; ks < 4; ++ks) {
        bf16x8 kf = *reinterpret_cast<const bf16x8*>(
            Kp + (size_t)(t0 + ct * 16 + lr) * HD + ks * 32 + lh * 8);
        s[ct] = __builtin_amdgcn_mfma_f32_16x16x32_bf16(qf[ks], kf, s[ct], 0, 0, 0);
      }
    // causal mask only on the diagonal tile
    if (it == ntiles - 1) {
#pragma unroll
      for (int ct = 0; ct < 4; ++ct) {
        int tcol = t0 + ct * 16 + lr;
#pragma unroll
        for (int r = 0; r < 4; ++r)
          if (tcol > qrow0 + lh * 4 + r) s[ct][r] = -1e30f;
      }
    }
    // online softmax (rows live in 16-lane groups; xor 1/2/4/8 reduces a row)
#pragma unroll
    for (int r = 0; r < 4; ++r) {
      float rm = fmaxf(fmaxf(s[0][r], s[1][r]), fmaxf(s[2][r], s[3][r]));
      rm = fmaxf(rm, __shfl_xor(rm, 1));
      rm = fmaxf(rm, __shfl_xor(rm, 2));
      rm = fmaxf(rm, __shfl_xor(rm, 4));
      rm = fmaxf(rm, __shfl_xor(rm, 8));
      float nm = fmaxf(mrun[r], rm);
      float fs = __expf(mrun[r] - nm);
      float rowsum = 0.f;
#pragma unroll
      for (int ct = 0; ct < 4; ++ct) {
        float p = __expf(s[ct][r] - nm);
        s[ct][r] = p;
        rowsum += p;
      }
      rowsum += __shfl_xor(rowsum, 1);
      rowsum += __shfl_xor(rowsum, 2);
      rowsum += __shfl_xor(rowsum, 4);
      rowsum += __shfl_xor(rowsum, 8);
      lrun[r] = lrun[r] * fs + rowsum;
      mrun[r] = nm;
#pragma unroll
      for (int cd = 0; cd < 8; ++cd) o[cd][r] *= fs;
    }
    // P (C-layout) -> bf16 LDS -> A-layout fragments (per-wave, no barrier)
#pragma unroll
    for (int ct = 0; ct < 4; ++ct)
#pragma unroll
      for (int r = 0; r < 4; ++r)
        Plds[w][lh * 4 + r][ct * 16 + lr] = f2bf(s[ct][r]);
    bf16x8 pf[2];
#pragma unroll
    for (int ks = 0; ks < 2; ++ks)
      pf[ks] = *reinterpret_cast<const bf16x8*>(&Plds[w][lr][ks * 32 + lh * 8]);
    // O += P V : 8 d-tiles x 2 t-steps
#pragma unroll
    for (int cd = 0; cd < 8; ++cd)
#pragma unroll
      for (int ks = 0; ks < 2; ++ks) {
        bf16x8 vf = *reinterpret_cast<const bf16x8*>(
            Vp + (size_t)(cd * 16 + lr) * T_SEQ + t0 + ks * 32 + lh * 8);
        o[cd] = __builtin_amdgcn_mfma_f32_16x16x32_bf16(pf[ks], vf, o[cd], 0, 0, 0);
      }
  }
  float inv[4];
#pragma unroll
  for (int r = 0; r < 4; ++r) inv[r] = 1.0f / lrun[r];
#pragma unroll
  for (int cd = 0; cd < 8; ++cd)
#pragma unroll
    for (int r = 0; r < 4; ++r) {
      int row = qrow0 + lh * 4 + r;
      int col = h * HD + cd * 16 + lr;
      O[((size_t)(b * T_SEQ + row)) * 2048 + col] = f2bf(o[cd][r] * inv[r]);
    }
}

// ---------------------------------------------------------------------------
extern "C" void kernel_launch(void* const* d_in, const int* in_sizes, int n_in,
                              void* d_out, int out_size, void* d_ws, size_t ws_size,
                              hipStream_t stream) {
  const float* x  = (const float*)d_in[0];
  const float* wq = (const float*)d_in[1];
  const float* wk = (const float*)d_in[2];
  const float* wv = (const float*)d_in[3];
  const float* wo = (const float*)d_in[4];
  float* out = (float*)d_out;

  char* ws = (char*)d_ws;
  size_t off = 0;
  auto alloc = [&](size_t bytes) {
    char* p = ws + off;
    off = (off + bytes + 255) & ~(size_t)255;
    return p;
  };
  u16* xb   = (u16*)alloc((size_t)BT * 2048 * 2);          // 16.8 MB (reused as Ob)
  u16* wqt  = (u16*)alloc((size_t)2048 * 2048 * 2);        //  8.4 MB
  u16* wkt  = (u16*)alloc((size_t)512 * 2048 * 2);         //  2.1 MB
  u16* wvt  = (u16*)alloc((size_t)512 * 2048 * 2);         //  2.1 MB
  u16* wot  = (u16*)alloc((size_t)2048 * 2048 * 2);        //  8.4 MB
  u16* Qb   = (u16*)alloc((size_t)BT * 2048 * 2);          // 16.8 MB
  u16* Kb   = (u16*)alloc((size_t)2 * NKVH * T_SEQ * HD * 2);  // 4.2 MB
  u16* Vb   = (u16*)alloc((size_t)2 * NKVH * T_SEQ * HD * 2);  // 4.2 MB
  u16* Vtb  = (u16*)alloc((size_t)2 * NKVH * T_SEQ * HD * 2);  // 4.2 MB
  float* tabc = (float*)alloc((size_t)T_SEQ * 64 * 4);     // 0.5 MB
  float* tabs = (float*)alloc((size_t)T_SEQ * 64 * 4);     // 0.5 MB
  u16* Ob = xb;  // xb dead after gemm<0>; reuse for attention output
  (void)in_sizes; (void)n_in; (void)out_size; (void)ws_size;

  // prep
  k_cast_x<<<dim3(8192), dim3(256), 0, stream>>>(x, xb);
  k_transpose_cast<<<dim3(64, 64), dim3(256), 0, stream>>>(wq, wqt, 2048, 2048);
  k_transpose_cast<<<dim3(16, 64), dim3(256), 0, stream>>>(wk, wkt, 2048, 512);
  k_transpose_cast<<<dim3(16, 64), dim3(256), 0, stream>>>(wv, wvt, 2048, 512);
  k_transpose_cast<<<dim3(64, 64), dim3(256), 0, stream>>>(wo, wot, 2048, 2048);
  k_rope_tables<<<dim3(512), dim3(256), 0, stream>>>(tabc, tabs);
  // QKV projection (fused N=3072)
  k_gemm<0><<<dim3(24, 32), dim3(256), 0, stream>>>(xb, wqt, wkt, wvt, Qb, Kb, Vb, nullptr);
  // RoPE in place (Q gets 1/sqrt(128) folded in); V -> Vt
  k_rope_apply<<<dim3(4096), dim3(256), 0, stream>>>(Qb, tabc, tabs, 0.08838834764831845f);
  k_rope_apply<<<dim3(1024), dim3(256), 0, stream>>>(Kb, tabc, tabs, 1.0f);
  k_transpose_v<<<dim3(4, 64, 8), dim3(256), 0, stream>>>(Vb, Vtb);
  // attention
  k_attn<<<dim3(1024), dim3(256), 0, stream>>>(Qb, Kb, Vtb, Ob);
  // output projection (fp32 out)
  k_gemm<1><<<dim3(16, 32), dim3(256), 0, stream>>>(Ob, wot, nullptr, nullptr,
                                                    nullptr, nullptr, nullptr, out);
}

// Round 4
// 505.604 us; speedup vs baseline: 1.3852x; 1.3852x over previous
//
#include <hip/hip_runtime.h>
#include <stdint.h>

// ---------------------------------------------------------------------------
// Attention block: out = softmax_causal( rope(xWq) rope(xWk)^T / sqrt(hd) ) (xWv) @ Wo
// B=2 T=2048 D=2048 H=16 KVH=4 hd=128. All fp32 in/out; internal bf16 MFMA.
// ---------------------------------------------------------------------------

#define T_SEQ 2048
#define NHEAD 16
#define NKVH  4
#define HD    128
#define BT    4096   // B*T

typedef unsigned short u16;
typedef __attribute__((ext_vector_type(8))) __bf16 bf16x8;
typedef __attribute__((ext_vector_type(8))) u16    u16x8;
typedef __attribute__((ext_vector_type(4))) u16    u16x4;
typedef __attribute__((ext_vector_type(4))) float  f32x4;

// fp32 -> bf16 RNE (finite inputs)
__device__ __forceinline__ u16 f2bf(float f) {
  uint32_t x = __float_as_uint(f);
  return (u16)((x + 0x7FFFu + ((x >> 16) & 1u)) >> 16);
}
__device__ __forceinline__ float bf2f(u16 u) {
  return __uint_as_float(((uint32_t)u) << 16);
}

// async global->LDS, 16B per lane (wave-uniform base + lane*16 dest)
__device__ __forceinline__ void gll16(const void* g, void* l) {
  __builtin_amdgcn_global_load_lds(
      (const __attribute__((address_space(1))) unsigned int*)g,
      (__attribute__((address_space(3))) unsigned int*)l, 16, 0, 0);
}

// ---------------------------------------------------------------------------
// prep kernels
// ---------------------------------------------------------------------------
__global__ __launch_bounds__(256) void k_cast_x(const float* __restrict__ src,
                                                u16* __restrict__ dst) {
  size_t id = (size_t)blockIdx.x * 256 + threadIdx.x;  // one float4 per thread
  f32x4 v = *reinterpret_cast<const f32x4*>(src + id * 4);
  u16x4 o;
  o[0] = f2bf(v[0]); o[1] = f2bf(v[1]); o[2] = f2bf(v[2]); o[3] = f2bf(v[3]);
  *reinterpret_cast<u16x4*>(dst + id * 4) = o;
}

// src [R][C] f32 (row-major) -> dst [C][R] bf16
__global__ __launch_bounds__(256) void k_transpose_cast(const float* __restrict__ src,
                                                        u16* __restrict__ dst,
                                                        int R, int C) {
  __shared__ float tile[32][33];
  int c0 = blockIdx.x * 32, r0 = blockIdx.y * 32;
  int tx = threadIdx.x & 31, ty = threadIdx.x >> 5;  // 32 x 8
#pragma unroll
  for (int i = 0; i < 4; ++i)
    tile[ty + i * 8][tx] = src[(size_t)(r0 + ty + i * 8) * C + c0 + tx];
  __syncthreads();
#pragma unroll
  for (int i = 0; i < 4; ++i)
    dst[(size_t)(c0 + ty + i * 8) * R + r0 + tx] = f2bf(tile[tx][ty + i * 8]);
}

// V [slice][t][d] bf16 -> Vt [slice][d][t] bf16, slice = b*NKVH+kvh
__global__ __launch_bounds__(256) void k_transpose_v(const u16* __restrict__ src,
                                                     u16* __restrict__ dst) {
  __shared__ u16 tile[32][34];
  int slice = blockIdx.z;
  src += (size_t)slice * T_SEQ * HD;
  dst += (size_t)slice * HD * T_SEQ;
  int d0 = blockIdx.x * 32, t0 = blockIdx.y * 32;
  int tx = threadIdx.x & 31, ty = threadIdx.x >> 5;
#pragma unroll
  for (int i = 0; i < 4; ++i)
    tile[ty + i * 8][tx] = src[(size_t)(t0 + ty + i * 8) * HD + d0 + tx];
  __syncthreads();
#pragma unroll
  for (int i = 0; i < 4; ++i)
    dst[(size_t)(d0 + ty + i * 8) * T_SEQ + t0 + tx] = tile[tx][ty + i * 8];
}

// cos/sin tables [T][64] fp32; freq_i = 10000^(-i/64)
__global__ __launch_bounds__(256) void k_rope_tables(float* __restrict__ tc,
                                                     float* __restrict__ ts) {
  int id = blockIdx.x * 256 + threadIdx.x;  // < 2048*64
  int pos = id >> 6, i = id & 63;
  float freq = exp2f(-(float)i * (13.287712379549449f / 64.0f));
  float ang = (float)pos * freq;
  tc[id] = cosf(ang);
  ts[id] = sinf(ang);
}

// in-place RoPE on [BH][T][128] bf16; scale folds 1/sqrt(hd) into Q
__global__ __launch_bounds__(256) void k_rope_apply(u16* __restrict__ buf,
                                                    const float* __restrict__ tc,
                                                    const float* __restrict__ ts,
                                                    float scale) {
  int id = blockIdx.x * 256 + threadIdx.x;
  int i8 = id & 15;                 // 8-elem chunk within head dim (4 pairs)
  int t  = (id >> 4) & (T_SEQ - 1);
  int bh = id >> 15;
  u16* p = buf + ((size_t)bh * T_SEQ + t) * HD + i8 * 8;
  u16x8 v = *reinterpret_cast<u16x8*>(p);
  f32x4 c = *reinterpret_cast<const f32x4*>(tc + t * 64 + i8 * 4);
  f32x4 s = *reinterpret_cast<const f32x4*>(ts + t * 64 + i8 * 4);
  u16x8 o;
#pragma unroll
  for (int j = 0; j < 4; ++j) {
    float x1 = bf2f(v[2 * j]), x2 = bf2f(v[2 * j + 1]);
    o[2 * j]     = f2bf((x1 * c[j] - x2 * s[j]) * scale);
    o[2 * j + 1] = f2bf((x1 * s[j] + x2 * c[j]) * scale);
  }
  *reinterpret_cast<u16x8*>(p) = o;
}

// ---------------------------------------------------------------------------
// m97-structure bf16 GEMM: C[M=4096][N] = A[4096][2048] * W, W given as Wt[N][2048].
// 128x128 tile, BK=32, 4 waves (2x2 of 64x64), global_load_lds staging.
// EPI=0: N=3072 fused QKV, epilogue scatters bf16 into Q/K/V head layouts.
// EPI=1: N=2048, epilogue stores fp32 to Cf.
// ---------------------------------------------------------------------------
template <int EPI>
__global__ __launch_bounds__(256) void k_gemm(const u16* __restrict__ A,
                                              const u16* __restrict__ W0,
                                              const u16* __restrict__ W1,
                                              const u16* __restrict__ W2,
                                              u16* __restrict__ Qb,
                                              u16* __restrict__ Kb,
                                              u16* __restrict__ Vb,
                                              float* __restrict__ Cf) {
  __shared__ u16 As[128 * 32];
  __shared__ u16 Bs[128 * 32];
  int t = threadIdx.x;
  int bx = blockIdx.x, by = blockIdx.y;
  int ncol0 = bx * 128;
  const u16* Bt;
  if (EPI == 0) {
    if (ncol0 < 2048)      Bt = W0 + (size_t)ncol0 * 2048;
    else if (ncol0 < 2560) Bt = W1 + (size_t)(ncol0 - 2048) * 2048;
    else                   Bt = W2 + (size_t)(ncol0 - 2560) * 2048;
  } else {
    Bt = W0 + (size_t)ncol0 * 2048;
  }
  const u16* ga = A  + (size_t)(by * 128 + (t >> 2)) * 2048 + (t & 3) * 8;
  const u16* gb = Bt + (size_t)(t >> 2) * 2048 + (t & 3) * 8;
  int w = t >> 6, l = t & 63;
  int wr = w >> 1, wc = w & 1;
  int lr = l & 15, lh = l >> 4;
  f32x4 acc[4][4] = {};
  for (int kb = 0; kb < 2048; kb += 32) {
    __syncthreads();
    gll16(ga,             &As[t * 8]);
    gll16(ga + 64 * 2048, &As[2048 + t * 8]);
    gll16(gb,             &Bs[t * 8]);
    gll16(gb + 64 * 2048, &Bs[2048 + t * 8]);
    ga += 32; gb += 32;
    __syncthreads();
    bf16x8 af[4], bw[4];
#pragma unroll
    for (int fr = 0; fr < 4; ++fr)
      af[fr] = *reinterpret_cast<const bf16x8*>(&As[(wr * 64 + fr * 16 + lr) * 32 + lh * 8]);
#pragma unroll
    for (int fc = 0; fc < 4; ++fc)
      bw[fc] = *reinterpret_cast<const bf16x8*>(&Bs[(wc * 64 + fc * 16 + lr) * 32 + lh * 8]);
#pragma unroll
    for (int fr = 0; fr < 4; ++fr)
#pragma unroll
      for (int fc = 0; fc < 4; ++fc)
        acc[fr][fc] = __builtin_amdgcn_mfma_f32_16x16x32_bf16(af[fr], bw[fc], acc[fr][fc], 0, 0, 0);
  }
  int row0 = by * 128 + wr * 64;
  int col0 = ncol0 + wc * 64;
#pragma unroll
  for (int fr = 0; fr < 4; ++fr)
#pragma unroll
    for (int fc = 0; fc < 4; ++fc)
#pragma unroll
      for (int r = 0; r < 4; ++r) {
        int row = row0 + fr * 16 + lh * 4 + r;   // C/D: row=(l>>4)*4+reg, col=l&15
        int col = col0 + fc * 16 + lr;
        float v = acc[fr][fc][r];
        if (EPI == 1) {
          Cf[(size_t)row * 2048 + col] = v;
        } else {
          int b = row >> 11, tt = row & 2047;
          if (col < 2048) {
            int h = col >> 7, d = col & 127;
            Qb[((size_t)(b * NHEAD + h) * T_SEQ + tt) * HD + d] = f2bf(v);
          } else if (col < 2560) {
            int c2 = col - 2048; int h = c2 >> 7, d = c2 & 127;
            Kb[((size_t)(b * NKVH + h) * T_SEQ + tt) * HD + d] = f2bf(v);
          } else {
            int c2 = col - 2560; int h = c2 >> 7, d = c2 & 127;
            Vb[((size_t)(b * NKVH + h) * T_SEQ + tt) * HD + d] = f2bf(v);
          }
        }
      }
}

// ---------------------------------------------------------------------------
// Flash attention (causal, GQA), latency-optimized restructure (round 4):
//   * 1 wave per block (64 thr), one 16-row q-tile per wave -> grid 4096 =
//     16 blocks/CU, ALL resident (LDS 2.3KB, VGPR<=128 via launch_bounds(64,4))
//     vs old 12% avg occupancy with decaying triangular blocks.
//   * job decode: blk&7 = (b,kvh) slice -> pins each KV slice (1MB) to one
//     XCD's L2 (blockIdx%8 ~ XCD); (blk>>3)&15 = head-in-group/q-sub;
//     blk>>7 = work level (ntiles = 32-level), so every CU gets a balanced
//     mix of long and short jobs.
//   * K/V fragment loads explicitly double-buffered in register groups
//     (4-8 loads in flight instead of ~1) so ~200cy L2 latency overlaps
//     with MFMA/softmax instead of serializing (old tau ~16.7k cy/tile).
// K/V direct from global (L2-resident per XCD); online softmax in registers;
// P->bf16 via per-wave padded LDS (no barriers: wave-private data).
// Scale 1/sqrt(hd) pre-folded into Q by k_rope_apply.
// ---------------------------------------------------------------------------
__global__ __launch_bounds__(64, 4) void k_attn(const u16* __restrict__ Q,
                                                const u16* __restrict__ K,
                                                const u16* __restrict__ Vt,
                                                u16* __restrict__ O) {
  int blk = blockIdx.x;                  // 0..4095
  int slice = blk & 7;                   // b*4+kvh  (XCD-pinned)
  int j     = (blk >> 3) & 15;           // hg(2b) | q4(2b)
  int lvl   = blk >> 7;                  // 0..31
  int nt    = 32 - lvl;                  // KV-64 tiles for this job
  int q4    = j >> 2, hg = j & 3;
  int qt    = (nt - 1) * 4 + q4;         // 16-row q-tile, qt/4+1 == nt
  int b = slice >> 2, kvh = slice & 3;
  int h = kvh * 4 + hg;
  int l = threadIdx.x;
  int lr = l & 15, lh = l >> 4;
  int qrow0 = qt * 16;

  const u16* Qp = Q  + ((size_t)(b * NHEAD + h) * T_SEQ) * HD;
  const u16* Kp = K  + ((size_t)(b * NKVH + kvh) * T_SEQ) * HD;
  const u16* Vp = Vt + ((size_t)(b * NKVH + kvh) * HD) * T_SEQ;  // [d][t]

  __shared__ u16 Plds[16][72];  // stride 72 (144B) -> 2-way conflicts only

  bf16x8 qf[4];
#pragma unroll
  for (int ks = 0; ks < 4; ++ks)
    qf[ks] = *reinterpret_cast<const bf16x8*>(Qp + (size_t)(qrow0 + lr) * HD + ks * 32 + lh * 8);

  f32x4 o[8] = {};
  float mrun[4], lrun[4];
#pragma unroll
  for (int r = 0; r < 4; ++r) { mrun[r] = -1e30f; lrun[r] = 0.f; }

  for (int it = 0; it < nt; ++it) {
    int t0 = it * 64;
    const u16* Kt = Kp + (size_t)t0 * HD + lh * 8;     // + (ct*16+lr)*HD + ks*32
    const u16* Vtp = Vp + t0 + lh * 8;                 // + (cd*16+lr)*T_SEQ + ks*32

    // ---- S = Q K^T, K-fragments double-buffered (4 in flight per group) ----
    f32x4 s[4] = {};
    bf16x8 ka[4], kb[4];
#pragma unroll
    for (int ks = 0; ks < 4; ++ks)
      ka[ks] = *reinterpret_cast<const bf16x8*>(Kt + (size_t)(0 * 16 + lr) * HD + ks * 32);
#pragma unroll
    for (int ks = 0; ks < 4; ++ks)
      kb[ks] = *reinterpret_cast<const bf16x8*>(Kt + (size_t)(1 * 16 + lr) * HD + ks * 32);
#pragma unroll
    for (int ks = 0; ks < 4; ++ks)
      s[0] = __builtin_amdgcn_mfma_f32_16x16x32_bf16(qf[ks], ka[ks], s[0], 0, 0, 0);
#pragma unroll
    for (int ks = 0; ks < 4; ++ks)
      ka[ks] = *reinterpret_cast<const bf16x8*>(Kt + (size_t)(2 * 16 + lr) * HD + ks * 32);
#pragma unroll
    for (int ks = 0; ks < 4; ++ks)
      s[1] = __builtin_amdgcn_mfma_f32_16x16x32_bf16(qf[ks], kb[ks], s[1], 0, 0, 0);
#pragma unroll
    for (int ks = 0; ks < 4; ++ks)
      kb[ks] = *reinterpret_cast<const bf16x8*>(Kt + (size_t)(3 * 16 + lr) * HD + ks * 32);
#pragma unroll
    for (int ks = 0; ks < 4; ++ks)
      s[2] = __builtin_amdgcn_mfma_f32_16x16x32_bf16(qf[ks], ka[ks], s[2], 0, 0, 0);
#pragma unroll
    for (int ks = 0; ks < 4; ++ks)
      s[3] = __builtin_amdgcn_mfma_f32_16x16x32_bf16(qf[ks], kb[ks], s[3], 0, 0, 0);

    // ---- prefetch V (cd 0..3, ks0) so softmax hides its latency ----
    bf16x8 va[4], vb[4];
#pragma unroll
    for (int q = 0; q < 4; ++q)
      va[q] = *reinterpret_cast<const bf16x8*>(Vtp + (size_t)(q * 16 + lr) * T_SEQ);

    // causal mask only on the final (diagonal-containing) tile
    if (it == nt - 1) {
#pragma unroll
      for (int ct = 0; ct < 4; ++ct) {
        int tcol = t0 + ct * 16 + lr;
#pragma unroll
        for (int r = 0; r < 4; ++r)
          if (tcol > qrow0 + lh * 4 + r) s[ct][r] = -1e30f;
      }
    }
    // ---- online softmax (rows in 16-lane groups; xor 1/2/4/8 reduce) ----
#pragma unroll
    for (int r = 0; r < 4; ++r) {
      float rm = fmaxf(fmaxf(s[0][r], s[1][r]), fmaxf(s[2][r], s[3][r]));
      rm = fmaxf(rm, __shfl_xor(rm, 1));
      rm = fmaxf(rm, __shfl_xor(rm, 2));
      rm = fmaxf(rm, __shfl_xor(rm, 4));
      rm = fmaxf(rm, __shfl_xor(rm, 8));
      float nm = fmaxf(mrun[r], rm);
      float fs = __expf(mrun[r] - nm);
      float rowsum = 0.f;
#pragma unroll
      for (int ct = 0; ct < 4; ++ct) {
        float p = __expf(s[ct][r] - nm);
        s[ct][r] = p;
        rowsum += p;
      }
      rowsum += __shfl_xor(rowsum, 1);
      rowsum += __shfl_xor(rowsum, 2);
      rowsum += __shfl_xor(rowsum, 4);
      rowsum += __shfl_xor(rowsum, 8);
      lrun[r] = lrun[r] * fs + rowsum;
      mrun[r] = nm;
#pragma unroll
      for (int cd = 0; cd < 8; ++cd) o[cd][r] *= fs;
    }
    // ---- P (C-layout) -> bf16 LDS -> A-layout fragments (wave-private) ----
#pragma unroll
    for (int ct = 0; ct < 4; ++ct)
#pragma unroll
      for (int r = 0; r < 4; ++r)
        Plds[lh * 4 + r][ct * 16 + lr] = f2bf(s[ct][r]);
    bf16x8 pf[2];
#pragma unroll
    for (int ks = 0; ks < 2; ++ks)
      pf[ks] = *reinterpret_cast<const bf16x8*>(&Plds[lr][ks * 32 + lh * 8]);

    // ---- O += P V, V-fragments double-buffered ----
#pragma unroll
    for (int q = 0; q < 4; ++q)   // ks1, cd 0..3
      vb[q] = *reinterpret_cast<const bf16x8*>(Vtp + (size_t)(q * 16 + lr) * T_SEQ + 32);
#pragma unroll
    for (int q = 0; q < 4; ++q)
      o[q] = __builtin_amdgcn_mfma_f32_16x16x32_bf16(pf[0], va[q], o[q], 0, 0, 0);
#pragma unroll
    for (int q = 0; q < 4; ++q)   // ks0, cd 4..7
      va[q] = *reinterpret_cast<const bf16x8*>(Vtp + (size_t)((q + 4) * 16 + lr) * T_SEQ);
#pragma unroll
    for (int q = 0; q < 4; ++q)
      o[q] = __builtin_amdgcn_mfma_f32_16x16x32_bf16(pf[1], vb[q], o[q], 0, 0, 0);
#pragma unroll
    for (int q = 0; q < 4; ++q)   // ks1, cd 4..7
      vb[q] = *reinterpret_cast<const bf16x8*>(Vtp + (size_t)((q + 4) * 16 + lr) * T_SEQ + 32);
#pragma unroll
    for (int q = 0; q < 4; ++q)
      o[q + 4] = __builtin_amdgcn_mfma_f32_16x16x32_bf16(pf[0], va[q], o[q + 4], 0, 0, 0);
#pragma unroll
    for (int q = 0; q < 4; ++q)
      o[q + 4] = __builtin_amdgcn_mfma_f32_16x16x32_bf16(pf[1], vb[q], o[q + 4], 0, 0, 0);
  }
  float inv[4];
#pragma unroll
  for (int r = 0; r < 4; ++r) inv[r] = 1.0f / lrun[r];
#pragma unroll
  for (int cd = 0; cd < 8; ++cd)
#pragma unroll
    for (int r = 0; r < 4; ++r) {
      int row = qrow0 + lh * 4 + r;
      int col = h * HD + cd * 16 + lr;
      O[((size_t)(b * T_SEQ + row)) * 2048 + col] = f2bf(o[cd][r] * inv[r]);
    }
}

// ---------------------------------------------------------------------------
extern "C" void kernel_launch(void* const* d_in, const int* in_sizes, int n_in,
                              void* d_out, int out_size, void* d_ws, size_t ws_size,
                              hipStream_t stream) {
  const float* x  = (const float*)d_in[0];
  const float* wq = (const float*)d_in[1];
  const float* wk = (const float*)d_in[2];
  const float* wv = (const float*)d_in[3];
  const float* wo = (const float*)d_in[4];
  float* out = (float*)d_out;

  char* ws = (char*)d_ws;
  size_t off = 0;
  auto alloc = [&](size_t bytes) {
    char* p = ws + off;
    off = (off + bytes + 255) & ~(size_t)255;
    return p;
  };
  u16* xb   = (u16*)alloc((size_t)BT * 2048 * 2);          // 16.8 MB (reused as Ob)
  u16* wqt  = (u16*)alloc((size_t)2048 * 2048 * 2);        //  8.4 MB
  u16* wkt  = (u16*)alloc((size_t)512 * 2048 * 2);         //  2.1 MB
  u16* wvt  = (u16*)alloc((size_t)512 * 2048 * 2);         //  2.1 MB
  u16* wot  = (u16*)alloc((size_t)2048 * 2048 * 2);        //  8.4 MB
  u16* Qb   = (u16*)alloc((size_t)BT * 2048 * 2);          // 16.8 MB
  u16* Kb   = (u16*)alloc((size_t)2 * NKVH * T_SEQ * HD * 2);  // 4.2 MB
  u16* Vb   = (u16*)alloc((size_t)2 * NKVH * T_SEQ * HD * 2);  // 4.2 MB
  u16* Vtb  = (u16*)alloc((size_t)2 * NKVH * T_SEQ * HD * 2);  // 4.2 MB
  float* tabc = (float*)alloc((size_t)T_SEQ * 64 * 4);     // 0.5 MB
  float* tabs = (float*)alloc((size_t)T_SEQ * 64 * 4);     // 0.5 MB
  u16* Ob = xb;  // xb dead after gemm<0>; reuse for attention output
  (void)in_sizes; (void)n_in; (void)out_size; (void)ws_size;

  // prep
  k_cast_x<<<dim3(8192), dim3(256), 0, stream>>>(x, xb);
  k_transpose_cast<<<dim3(64, 64), dim3(256), 0, stream>>>(wq, wqt, 2048, 2048);
  k_transpose_cast<<<dim3(16, 64), dim3(256), 0, stream>>>(wk, wkt, 2048, 512);
  k_transpose_cast<<<dim3(16, 64), dim3(256), 0, stream>>>(wv, wvt, 2048, 512);
  k_transpose_cast<<<dim3(64, 64), dim3(256), 0, stream>>>(wo, wot, 2048, 2048);
  k_rope_tables<<<dim3(512), dim3(256), 0, stream>>>(tabc, tabs);
  // QKV projection (fused N=3072)
  k_gemm<0><<<dim3(24, 32), dim3(256), 0, stream>>>(xb, wqt, wkt, wvt, Qb, Kb, Vb, nullptr);
  // RoPE in place (Q gets 1/sqrt(128) folded in); V -> Vt
  k_rope_apply<<<dim3(4096), dim3(256), 0, stream>>>(Qb, tabc, tabs, 0.08838834764831845f);
  k_rope_apply<<<dim3(1024), dim3(256), 0, stream>>>(Kb, tabc, tabs, 1.0f);
  k_transpose_v<<<dim3(4, 64, 8), dim3(256), 0, stream>>>(Vb, Vtb);
  // attention: 4096 one-wave jobs, XCD-pinned KV slices, balanced levels
  k_attn<<<dim3(4096), dim3(64), 0, stream>>>(Qb, Kb, Vtb, Ob);
  // output projection (fp32 out)
  k_gemm<1><<<dim3(16, 32), dim3(256), 0, stream>>>(Ob, wot, nullptr, nullptr,
                                                    nullptr, nullptr, nullptr, out);
}

// Round 5
// 332.282 us; speedup vs baseline: 2.1078x; 1.5216x over previous
//
#include <hip/hip_runtime.h>
#include <stdint.h>

// ---------------------------------------------------------------------------
// Attention block: out = softmax_causal( rope(xWq) rope(xWk)^T / sqrt(hd) ) (xWv) @ Wo
// B=2 T=2048 D=2048 H=16 KVH=4 hd=128. All fp32 in/out; internal bf16 MFMA.
// ---------------------------------------------------------------------------

#define T_SEQ 2048
#define NHEAD 16
#define NKVH  4
#define HD    128
#define BT    4096   // B*T

typedef unsigned short u16;
typedef __attribute__((ext_vector_type(8))) __bf16 bf16x8;
typedef __attribute__((ext_vector_type(8))) u16    u16x8;
typedef __attribute__((ext_vector_type(4))) u16    u16x4;
typedef __attribute__((ext_vector_type(4))) float  f32x4;

// fp32 -> bf16 RNE (finite inputs)
__device__ __forceinline__ u16 f2bf(float f) {
  uint32_t x = __float_as_uint(f);
  return (u16)((x + 0x7FFFu + ((x >> 16) & 1u)) >> 16);
}
__device__ __forceinline__ float bf2f(u16 u) {
  return __uint_as_float(((uint32_t)u) << 16);
}

// async global->LDS, 16B per lane (wave-uniform base + lane*16 dest)
__device__ __forceinline__ void gll16(const void* g, void* l) {
  __builtin_amdgcn_global_load_lds(
      (const __attribute__((address_space(1))) unsigned int*)g,
      (__attribute__((address_space(3))) unsigned int*)l, 16, 0, 0);
}

// ---------------------------------------------------------------------------
// prep kernels
// ---------------------------------------------------------------------------
__global__ __launch_bounds__(256) void k_cast_x(const float* __restrict__ src,
                                                u16* __restrict__ dst) {
  size_t id = (size_t)blockIdx.x * 256 + threadIdx.x;  // one float4 per thread
  f32x4 v = *reinterpret_cast<const f32x4*>(src + id * 4);
  u16x4 o;
  o[0] = f2bf(v[0]); o[1] = f2bf(v[1]); o[2] = f2bf(v[2]); o[3] = f2bf(v[3]);
  *reinterpret_cast<u16x4*>(dst + id * 4) = o;
}

// src [R][C] f32 (row-major) -> dst [C][R] bf16
__global__ __launch_bounds__(256) void k_transpose_cast(const float* __restrict__ src,
                                                        u16* __restrict__ dst,
                                                        int R, int C) {
  __shared__ float tile[32][33];
  int c0 = blockIdx.x * 32, r0 = blockIdx.y * 32;
  int tx = threadIdx.x & 31, ty = threadIdx.x >> 5;  // 32 x 8
#pragma unroll
  for (int i = 0; i < 4; ++i)
    tile[ty + i * 8][tx] = src[(size_t)(r0 + ty + i * 8) * C + c0 + tx];
  __syncthreads();
#pragma unroll
  for (int i = 0; i < 4; ++i)
    dst[(size_t)(c0 + ty + i * 8) * R + r0 + tx] = f2bf(tile[tx][ty + i * 8]);
}

// V [slice][t][d] bf16 -> Vt [slice][d][t] bf16, slice = b*NKVH+kvh
__global__ __launch_bounds__(256) void k_transpose_v(const u16* __restrict__ src,
                                                     u16* __restrict__ dst) {
  __shared__ u16 tile[32][34];
  int slice = blockIdx.z;
  src += (size_t)slice * T_SEQ * HD;
  dst += (size_t)slice * HD * T_SEQ;
  int d0 = blockIdx.x * 32, t0 = blockIdx.y * 32;
  int tx = threadIdx.x & 31, ty = threadIdx.x >> 5;
#pragma unroll
  for (int i = 0; i < 4; ++i)
    tile[ty + i * 8][tx] = src[(size_t)(t0 + ty + i * 8) * HD + d0 + tx];
  __syncthreads();
#pragma unroll
  for (int i = 0; i < 4; ++i)
    dst[(size_t)(d0 + ty + i * 8) * T_SEQ + t0 + tx] = tile[tx][ty + i * 8];
}

// cos/sin tables [T][64] fp32; freq_i = 10000^(-i/64)
__global__ __launch_bounds__(256) void k_rope_tables(float* __restrict__ tc,
                                                     float* __restrict__ ts) {
  int id = blockIdx.x * 256 + threadIdx.x;  // < 2048*64
  int pos = id >> 6, i = id & 63;
  float freq = exp2f(-(float)i * (13.287712379549449f / 64.0f));
  float ang = (float)pos * freq;
  tc[id] = cosf(ang);
  ts[id] = sinf(ang);
}

// in-place RoPE on [BH][T][128] bf16; scale folds 1/sqrt(hd) into Q
__global__ __launch_bounds__(256) void k_rope_apply(u16* __restrict__ buf,
                                                    const float* __restrict__ tc,
                                                    const float* __restrict__ ts,
                                                    float scale) {
  int id = blockIdx.x * 256 + threadIdx.x;
  int i8 = id & 15;                 // 8-elem chunk within head dim (4 pairs)
  int t  = (id >> 4) & (T_SEQ - 1);
  int bh = id >> 15;
  u16* p = buf + ((size_t)bh * T_SEQ + t) * HD + i8 * 8;
  u16x8 v = *reinterpret_cast<u16x8*>(p);
  f32x4 c = *reinterpret_cast<const f32x4*>(tc + t * 64 + i8 * 4);
  f32x4 s = *reinterpret_cast<const f32x4*>(ts + t * 64 + i8 * 4);
  u16x8 o;
#pragma unroll
  for (int j = 0; j < 4; ++j) {
    float x1 = bf2f(v[2 * j]), x2 = bf2f(v[2 * j + 1]);
    o[2 * j]     = f2bf((x1 * c[j] - x2 * s[j]) * scale);
    o[2 * j + 1] = f2bf((x1 * s[j] + x2 * c[j]) * scale);
  }
  *reinterpret_cast<u16x8*>(p) = o;
}

// ---------------------------------------------------------------------------
// m97-structure bf16 GEMM: C[M=4096][N] = A[4096][2048] * W, W given as Wt[N][2048].
// 128x128 tile, BK=32, 4 waves (2x2 of 64x64), global_load_lds staging.
// EPI=0: N=3072 fused QKV, epilogue scatters bf16 into Q/K/V head layouts.
// EPI=1: N=2048, epilogue stores fp32 to Cf.
// ---------------------------------------------------------------------------
template <int EPI>
__global__ __launch_bounds__(256) void k_gemm(const u16* __restrict__ A,
                                              const u16* __restrict__ W0,
                                              const u16* __restrict__ W1,
                                              const u16* __restrict__ W2,
                                              u16* __restrict__ Qb,
                                              u16* __restrict__ Kb,
                                              u16* __restrict__ Vb,
                                              float* __restrict__ Cf) {
  __shared__ u16 As[128 * 32];
  __shared__ u16 Bs[128 * 32];
  int t = threadIdx.x;
  int bx = blockIdx.x, by = blockIdx.y;
  int ncol0 = bx * 128;
  const u16* Bt;
  if (EPI == 0) {
    if (ncol0 < 2048)      Bt = W0 + (size_t)ncol0 * 2048;
    else if (ncol0 < 2560) Bt = W1 + (size_t)(ncol0 - 2048) * 2048;
    else                   Bt = W2 + (size_t)(ncol0 - 2560) * 2048;
  } else {
    Bt = W0 + (size_t)ncol0 * 2048;
  }
  const u16* ga = A  + (size_t)(by * 128 + (t >> 2)) * 2048 + (t & 3) * 8;
  const u16* gb = Bt + (size_t)(t >> 2) * 2048 + (t & 3) * 8;
  int w = t >> 6, l = t & 63;
  int wr = w >> 1, wc = w & 1;
  int lr = l & 15, lh = l >> 4;
  f32x4 acc[4][4] = {};
  for (int kb = 0; kb < 2048; kb += 32) {
    __syncthreads();
    gll16(ga,             &As[t * 8]);
    gll16(ga + 64 * 2048, &As[2048 + t * 8]);
    gll16(gb,             &Bs[t * 8]);
    gll16(gb + 64 * 2048, &Bs[2048 + t * 8]);
    ga += 32; gb += 32;
    __syncthreads();
    bf16x8 af[4], bw[4];
#pragma unroll
    for (int fr = 0; fr < 4; ++fr)
      af[fr] = *reinterpret_cast<const bf16x8*>(&As[(wr * 64 + fr * 16 + lr) * 32 + lh * 8]);
#pragma unroll
    for (int fc = 0; fc < 4; ++fc)
      bw[fc] = *reinterpret_cast<const bf16x8*>(&Bs[(wc * 64 + fc * 16 + lr) * 32 + lh * 8]);
#pragma unroll
    for (int fr = 0; fr < 4; ++fr)
#pragma unroll
      for (int fc = 0; fc < 4; ++fc)
        acc[fr][fc] = __builtin_amdgcn_mfma_f32_16x16x32_bf16(af[fr], bw[fc], acc[fr][fc], 0, 0, 0);
  }
  int row0 = by * 128 + wr * 64;
  int col0 = ncol0 + wc * 64;
#pragma unroll
  for (int fr = 0; fr < 4; ++fr)
#pragma unroll
    for (int fc = 0; fc < 4; ++fc)
#pragma unroll
      for (int r = 0; r < 4; ++r) {
        int row = row0 + fr * 16 + lh * 4 + r;   // C/D: row=(l>>4)*4+reg, col=l&15
        int col = col0 + fc * 16 + lr;
        float v = acc[fr][fc][r];
        if (EPI == 1) {
          Cf[(size_t)row * 2048 + col] = v;
        } else {
          int b = row >> 11, tt = row & 2047;
          if (col < 2048) {
            int h = col >> 7, d = col & 127;
            Qb[((size_t)(b * NHEAD + h) * T_SEQ + tt) * HD + d] = f2bf(v);
          } else if (col < 2560) {
            int c2 = col - 2048; int h = c2 >> 7, d = c2 & 127;
            Kb[((size_t)(b * NKVH + h) * T_SEQ + tt) * HD + d] = f2bf(v);
          } else {
            int c2 = col - 2560; int h = c2 >> 7, d = c2 & 127;
            Vb[((size_t)(b * NKVH + h) * T_SEQ + tt) * HD + d] = f2bf(v);
          }
        }
      }
}

// ---------------------------------------------------------------------------
// Flash attention v3 (round 5): shared-LDS staged K/V, 8 waves/block.
//  * 512 blocks x 512 thr. Jobs sharing one (slice=b*4+kvh, level) KV stream
//    are grouped: wave w -> head hg=w&3, q-subtile q4=half*2+(w>>2); all 8
//    waves consume the SAME K/V tiles -> staged ONCE into LDS via
//    global_load_lds (8x fewer global loads than r4), prefetched a full
//    compute phase ahead (K double-buffered; V staged at iter start,
//    consumed after QK+softmax).
//  * T2 XOR swizzle via pre-swizzled GLOBAL source (linear LDS dest, rule21):
//    phys = logical ^ ((row&7)<<4). Without it ds_read_b128 of 16 rows at
//    256B/128B stride is a 16-way bank conflict.
//  * slice = blk&7 pins each 2MB K+Vt slice to one XCD's L2.
//  * level pairing lvl = g<16 ? g : 47-g makes each CU's two resident blocks
//    sum to exactly 33 KV-tiles -> flat balance, flat occupancy.
//  * __syncthreads (not raw barrier): loads were issued a phase early, so the
//    vmcnt(0) drain is ~free; no race risk on a fresh sync structure.
// ---------------------------------------------------------------------------
__global__ __launch_bounds__(512, 4) void k_attn(const u16* __restrict__ Q,
                                                 const u16* __restrict__ K,
                                                 const u16* __restrict__ Vt,
                                                 u16* __restrict__ O) {
  __shared__ u16 KbS[2][64 * 128];   // 2 x 16KB, rows 256B
  __shared__ u16 VbS[128 * 64];      // 16KB, rows 128B ([d][t] tile)
  __shared__ u16 Plds[8][16][72];    // per-wave P roundtrip, stride 144B

  int blk   = blockIdx.x;            // 0..511
  int slice = blk & 7;               // b*4+kvh (XCD-pinned: blk%8)
  int half  = (blk >> 3) & 1;
  int g     = blk >> 4;              // 0..31
  int lvl   = (g < 16) ? g : 47 - g; // pair levels L and 31-L across the grid
  int nt    = 32 - lvl;              // KV-64 tiles for this block (uniform!)
  int w = threadIdx.x >> 6, l = threadIdx.x & 63;
  int lr = l & 15, lh = l >> 4;
  int hg = w & 3, q4 = half * 2 + (w >> 2);
  int qrow0 = ((nt - 1) * 4 + q4) * 16;
  int b = slice >> 2, kvh = slice & 3, h = kvh * 4 + hg;

  const u16* Qp = Q  + ((size_t)(b * NHEAD + h) * T_SEQ) * HD;
  const u16* Kp = K  + ((size_t)(b * NKVH + kvh) * T_SEQ) * HD;
  const u16* Vp = Vt + ((size_t)(b * NKVH + kvh) * HD) * T_SEQ;  // [d][t]

  bf16x8 qf[4];
#pragma unroll
  for (int ks = 0; ks < 4; ++ks)
    qf[ks] = *reinterpret_cast<const bf16x8*>(Qp + (size_t)(qrow0 + lr) * HD + ks * 32 + lh * 8);

  f32x4 o[8] = {};
  float mrun[4], lrun[4];
#pragma unroll
  for (int r = 0; r < 4; ++r) { mrun[r] = -1e30f; lrun[r] = 0.f; }

  int kx = (lr & 7) << 4;  // XOR swizzle key (bits 6:4), row&7 == lr&7

  // ---- prologue: stage K tile 0 into KbS[0] (16KB, 2 calls/wave) ----
#pragma unroll
  for (int i = 0; i < 2; ++i) {
    int L = (w * 2 + i) * 1024 + l * 16;          // physical LDS byte offset
    int P = L ^ (((L >> 8) & 7) << 4);            // logical byte offset (row=P>>8)
    gll16((const char*)Kp + P, (char*)KbS[0] + L);
  }
  __syncthreads();

  int cur = 0;
  for (int it = 0; it < nt; ++it) {
    int t0 = it * 64;
    // ---- stage V(it) + K(it+1): issued now, consumed a phase later ----
#pragma unroll
    for (int i = 0; i < 2; ++i) {
      int L = (w * 2 + i) * 1024 + l * 16;
      int P = L ^ (((L >> 7) & 7) << 4);          // V rows are 128B (row=P>>7)
      int d = P >> 7, tb = P & 127;
      gll16((const char*)(Vp + t0) + (size_t)d * (T_SEQ * 2) + tb, (char*)VbS + L);
    }
    if (it + 1 < nt) {
#pragma unroll
      for (int i = 0; i < 2; ++i) {
        int L = (w * 2 + i) * 1024 + l * 16;
        int P = L ^ (((L >> 8) & 7) << 4);
        gll16((const char*)Kp + (size_t)(t0 + 64) * 256 + P, (char*)KbS[cur ^ 1] + L);
      }
    }
    // ---- S = Q K^T from swizzled LDS ----
    const char* kb = (const char*)KbS[cur];
    f32x4 s[4] = {};
#pragma unroll
    for (int ct = 0; ct < 4; ++ct) {
      bf16x8 kf[4];
#pragma unroll
      for (int ks = 0; ks < 4; ++ks)
        kf[ks] = *reinterpret_cast<const bf16x8*>(
            kb + ct * 4096 + lr * 256 + ((ks * 64 + lh * 16) ^ kx));
#pragma unroll
      for (int ks = 0; ks < 4; ++ks)
        s[ct] = __builtin_amdgcn_mfma_f32_16x16x32_bf16(qf[ks], kf[ks], s[ct], 0, 0, 0);
    }
    // causal mask only on the final (diagonal) tile
    if (it == nt - 1) {
#pragma unroll
      for (int ct = 0; ct < 4; ++ct) {
        int tcol = t0 + ct * 16 + lr;
#pragma unroll
        for (int r = 0; r < 4; ++r)
          if (tcol > qrow0 + lh * 4 + r) s[ct][r] = -1e30f;
      }
    }
    // ---- online softmax (rows in 16-lane groups; xor 1/2/4/8 reduce) ----
#pragma unroll
    for (int r = 0; r < 4; ++r) {
      float rm = fmaxf(fmaxf(s[0][r], s[1][r]), fmaxf(s[2][r], s[3][r]));
      rm = fmaxf(rm, __shfl_xor(rm, 1));
      rm = fmaxf(rm, __shfl_xor(rm, 2));
      rm = fmaxf(rm, __shfl_xor(rm, 4));
      rm = fmaxf(rm, __shfl_xor(rm, 8));
      float nm = fmaxf(mrun[r], rm);
      float fs = __expf(mrun[r] - nm);
      float rowsum = 0.f;
#pragma unroll
      for (int ct = 0; ct < 4; ++ct) {
        float p = __expf(s[ct][r] - nm);
        s[ct][r] = p;
        rowsum += p;
      }
      rowsum += __shfl_xor(rowsum, 1);
      rowsum += __shfl_xor(rowsum, 2);
      rowsum += __shfl_xor(rowsum, 4);
      rowsum += __shfl_xor(rowsum, 8);
      lrun[r] = lrun[r] * fs + rowsum;
      mrun[r] = nm;
#pragma unroll
      for (int cd = 0; cd < 8; ++cd) o[cd][r] *= fs;
    }
    // ---- P (C-layout) -> bf16 LDS -> A-layout fragments (wave-private) ----
#pragma unroll
    for (int ct = 0; ct < 4; ++ct)
#pragma unroll
      for (int r = 0; r < 4; ++r)
        Plds[w][lh * 4 + r][ct * 16 + lr] = f2bf(s[ct][r]);
    bf16x8 pf[2];
#pragma unroll
    for (int ks = 0; ks < 2; ++ks)
      pf[ks] = *reinterpret_cast<const bf16x8*>(&Plds[w][lr][ks * 32 + lh * 8]);

    __syncthreads();  // V(it) staged & visible (loads issued a phase ago)

    // ---- O += P V from swizzled LDS ----
    const char* vb = (const char*)VbS;
#pragma unroll
    for (int cd = 0; cd < 8; ++cd) {
      bf16x8 vf0 = *reinterpret_cast<const bf16x8*>(
          vb + cd * 2048 + lr * 128 + ((0 * 64 + lh * 16) ^ kx));
      bf16x8 vf1 = *reinterpret_cast<const bf16x8*>(
          vb + cd * 2048 + lr * 128 + ((1 * 64 + lh * 16) ^ kx));
      o[cd] = __builtin_amdgcn_mfma_f32_16x16x32_bf16(pf[0], vf0, o[cd], 0, 0, 0);
      o[cd] = __builtin_amdgcn_mfma_f32_16x16x32_bf16(pf[1], vf1, o[cd], 0, 0, 0);
    }
    __syncthreads();  // all reads of VbS/KbS[cur] done; K(it+1) visible
    cur ^= 1;
  }
  float inv[4];
#pragma unroll
  for (int r = 0; r < 4; ++r) inv[r] = 1.0f / lrun[r];
#pragma unroll
  for (int cd = 0; cd < 8; ++cd)
#pragma unroll
    for (int r = 0; r < 4; ++r) {
      int row = qrow0 + lh * 4 + r;
      int col = h * HD + cd * 16 + lr;
      O[((size_t)(b * T_SEQ + row)) * 2048 + col] = f2bf(o[cd][r] * inv[r]);
    }
}

// ---------------------------------------------------------------------------
extern "C" void kernel_launch(void* const* d_in, const int* in_sizes, int n_in,
                              void* d_out, int out_size, void* d_ws, size_t ws_size,
                              hipStream_t stream) {
  const float* x  = (const float*)d_in[0];
  const float* wq = (const float*)d_in[1];
  const float* wk = (const float*)d_in[2];
  const float* wv = (const float*)d_in[3];
  const float* wo = (const float*)d_in[4];
  float* out = (float*)d_out;

  char* ws = (char*)d_ws;
  size_t off = 0;
  auto alloc = [&](size_t bytes) {
    char* p = ws + off;
    off = (off + bytes + 255) & ~(size_t)255;
    return p;
  };
  u16* xb   = (u16*)alloc((size_t)BT * 2048 * 2);          // 16.8 MB (reused as Ob)
  u16* wqt  = (u16*)alloc((size_t)2048 * 2048 * 2);        //  8.4 MB
  u16* wkt  = (u16*)alloc((size_t)512 * 2048 * 2);         //  2.1 MB
  u16* wvt  = (u16*)alloc((size_t)512 * 2048 * 2);         //  2.1 MB
  u16* wot  = (u16*)alloc((size_t)2048 * 2048 * 2);        //  8.4 MB
  u16* Qb   = (u16*)alloc((size_t)BT * 2048 * 2);          // 16.8 MB
  u16* Kb   = (u16*)alloc((size_t)2 * NKVH * T_SEQ * HD * 2);  // 4.2 MB
  u16* Vb   = (u16*)alloc((size_t)2 * NKVH * T_SEQ * HD * 2);  // 4.2 MB
  u16* Vtb  = (u16*)alloc((size_t)2 * NKVH * T_SEQ * HD * 2);  // 4.2 MB
  float* tabc = (float*)alloc((size_t)T_SEQ * 64 * 4);     // 0.5 MB
  float* tabs = (float*)alloc((size_t)T_SEQ * 64 * 4);     // 0.5 MB
  u16* Ob = xb;  // xb dead after gemm<0>; reuse for attention output
  (void)in_sizes; (void)n_in; (void)out_size; (void)ws_size;

  // prep
  k_cast_x<<<dim3(8192), dim3(256), 0, stream>>>(x, xb);
  k_transpose_cast<<<dim3(64, 64), dim3(256), 0, stream>>>(wq, wqt, 2048, 2048);
  k_transpose_cast<<<dim3(16, 64), dim3(256), 0, stream>>>(wk, wkt, 2048, 512);
  k_transpose_cast<<<dim3(16, 64), dim3(256), 0, stream>>>(wv, wvt, 2048, 512);
  k_transpose_cast<<<dim3(64, 64), dim3(256), 0, stream>>>(wo, wot, 2048, 2048);
  k_rope_tables<<<dim3(512), dim3(256), 0, stream>>>(tabc, tabs);
  // QKV projection (fused N=3072)
  k_gemm<0><<<dim3(24, 32), dim3(256), 0, stream>>>(xb, wqt, wkt, wvt, Qb, Kb, Vb, nullptr);
  // RoPE in place (Q gets 1/sqrt(128) folded in); V -> Vt
  k_rope_apply<<<dim3(4096), dim3(256), 0, stream>>>(Qb, tabc, tabs, 0.08838834764831845f);
  k_rope_apply<<<dim3(1024), dim3(256), 0, stream>>>(Kb, tabc, tabs, 1.0f);
  k_transpose_v<<<dim3(4, 64, 8), dim3(256), 0, stream>>>(Vb, Vtb);
  // attention: 512 blocks x 8 waves, LDS-staged K/V, XCD-pinned, level-paired
  k_attn<<<dim3(512), dim3(512), 0, stream>>>(Qb, Kb, Vtb, Ob);
  // output projection (fp32 out)
  k_gemm<1><<<dim3(16, 32), dim3(256), 0, stream>>>(Ob, wot, nullptr, nullptr,
                                                    nullptr, nullptr, nullptr, out);
}